// Round 1
// baseline (172.356 us; speedup 1.0000x reference)
//
#include <hip/hip_runtime.h>
#include <hip/hip_bf16.h>

// Problem constants (from reference setup_inputs): B=8, C=3, H=W=512
#define HW   262144      // 512*512 (2^18)
#define BC   24          // B*C channels
#define NB   256         // bins
#define NTOT 6291456     // B*C*H*W

// Workspace layout (bytes):
//   [0, 24576)        hist_s  : int[24][256]
//   [24576, 49152)    hist_r  : int[24][256]
//   [49152, 73728)    lut     : float[24][256]
//   [73728, 73732)    accum   : float
#define WS_HS_OFF   0
#define WS_HR_OFF   24576
#define WS_LUT_OFF  49152
#define WS_ACC_OFF  73728
#define WS_BYTES    73732

__device__ __forceinline__ int quantize(float x, float m) {
    // jnp.clip(jnp.round((x+1)*0.5*255 * m), 0, 255)
    float v = (x + 1.0f) * 0.5f * 255.0f * m;
    float r = rintf(v);
    r = fminf(fmaxf(r, 0.0f), 255.0f);
    return (int)r;
}

// ---------------- Stage 1: per-channel histograms ----------------
__global__ void hist_kernel(const float* __restrict__ ref,
                            const float* __restrict__ tar,
                            const float* __restrict__ msrc,
                            const float* __restrict__ mtar,
                            int* __restrict__ hs, int* __restrict__ hr) {
    __shared__ int lhs[NB];
    __shared__ int lhr[NB];
    const int t = threadIdx.x;          // blockDim.x == 256
    lhs[t] = 0;
    lhr[t] = 0;
    __syncthreads();

    const int c = blockIdx.y;           // channel 0..23
    const int b = c / 3;
    const float* refc = ref + (size_t)c * HW;
    const float* tarc = tar + (size_t)c * HW;
    const float* ms   = msrc + (size_t)b * HW;
    const float* mt   = mtar + (size_t)b * HW;

    const int stride = gridDim.x * blockDim.x;
    for (int p = blockIdx.x * blockDim.x + t; p < HW; p += stride) {
        int qs = quantize(refc[p], ms[p]);
        int qr = quantize(tarc[p], mt[p]);
        atomicAdd(&lhs[qs], 1);
        atomicAdd(&lhr[qr], 1);
    }
    __syncthreads();
    if (lhs[t]) atomicAdd(&hs[c * NB + t], lhs[t]);
    if (lhr[t]) atomicAdd(&hr[c * NB + t], lhr[t]);
}

// ---------------- Stage 2: per-channel matching LUT ----------------
// One block (256 threads) per channel. Thread t owns bin t.
__device__ __forceinline__ int incl_scan256(int v, int t, int* buf) {
    buf[t] = v;
    __syncthreads();
#pragma unroll
    for (int off = 1; off < NB; off <<= 1) {
        int x = (t >= off) ? buf[t - off] : 0;
        __syncthreads();
        buf[t] += x;
        __syncthreads();
    }
    return buf[t];
}

__global__ void lut_kernel(const int* __restrict__ hs,
                           const int* __restrict__ hr,
                           float* __restrict__ lut) {
    const int c = blockIdx.x;
    const int t = threadIdx.x;

    __shared__ int buf[NB];
    __shared__ float xp[NB];
    __shared__ float fp[NB];
    __shared__ int firstS, firstR, nOccS, nOccR;

    const int cs = hs[c * NB + t];
    const int cr = hr[c * NB + t];

    if (t == 0) { firstS = NB; firstR = NB; nOccS = 0; nOccR = 0; }
    __syncthreads();
    if (cs > 0) { atomicMin(&firstS, t); atomicAdd(&nOccS, 1); }
    if (cr > 0) { atomicMin(&firstR, t); atomicAdd(&nOccR, 1); }
    __syncthreads();

    // zero the first occupied bin on each side (reference drops it)
    const int csz = (t == firstS) ? 0 : cs;
    const int crz = (t == firstR) ? 0 : cr;

    // source quantiles
    const int cumS = incl_scan256(csz, t, buf);
    const int totS = buf[NB - 1];
    __syncthreads();
    // reference quantiles
    const int cumR = incl_scan256(crz, t, buf);
    const int totR = buf[NB - 1];
    __syncthreads();
    // compaction rank for occupied reference bins (excluding firstR)
    const int occ2 = (cr > 0 && t != firstR) ? 1 : 0;
    const int rank = incl_scan256(occ2, t, buf) - occ2;  // exclusive
    __syncthreads();

    const float x  = (float)cumS / fmaxf((float)totS, 1.0f);  // s_q at bin t
    const float rq = (float)cumR / fmaxf((float)totR, 1.0f);  // r_q at bin t

    xp[t] = 2.0f;  // pad value > any query (queries <= 1.0)
    fp[t] = 0.0f;
    __syncthreads();
    if (occ2) { xp[rank] = rq; fp[rank] = (float)t; }
    __syncthreads();

    // jnp.interp(x, xp, fp):
    //   i = clip(searchsorted(xp, x, side='right'), 1, 255)
    //   f = fp[i-1] + (x - xp[i-1]) / (xp[i]-xp[i-1]) * (fp[i]-fp[i-1])
    //   (dx == 0 -> fp[i]);  x < xp[0] -> fp[0]
    int lo = 0, hi = NB;
    while (lo < hi) {
        int mid = (lo + hi) >> 1;
        if (xp[mid] > x) hi = mid; else lo = mid + 1;
    }
    int i = lo;
    i = (i < 1) ? 1 : ((i > NB - 1) ? NB - 1 : i);
    float dxv = xp[i] - xp[i - 1];
    float f;
    if (dxv == 0.0f) {
        f = fp[i];
    } else {
        f = fp[i - 1] + (x - xp[i - 1]) / dxv * (fp[i] - fp[i - 1]);
    }
    if (x < xp[0]) f = fp[0];

    float l = truncf(f);
    if (t == firstS) l = 0.0f;
    const bool ok = (nOccS > 1) && (nOccR > 1);
    if (!ok) l = 0.0f;

    lut[c * NB + t] = l;
}

// ---------------- Stage 3: apply LUT + masked L1 reduction ----------------
__global__ void loss_kernel(const float* __restrict__ inp,
                            const float* __restrict__ ref,
                            const float* __restrict__ msrc,
                            const float* __restrict__ lut,
                            float* __restrict__ accum) {
    float s = 0.0f;
    const int stride = gridDim.x * blockDim.x;
    for (int idx = blockIdx.x * blockDim.x + threadIdx.x; idx < NTOT; idx += stride) {
        const int c = idx >> 18;           // channel (HW = 2^18)
        const int p = idx & (HW - 1);
        const float m = msrc[(size_t)(c / 3) * HW + p];
        const int q = quantize(ref[idx], m);
        const float matched = lut[c * NB + q];
        const float im = (inp[idx] + 1.0f) * 0.5f * 255.0f * m;
        s += fabsf(im - matched * m);
    }

    // wave (64-lane) shuffle reduction
#pragma unroll
    for (int off = 32; off > 0; off >>= 1) s += __shfl_down(s, off);

    __shared__ float wsum[4];              // 256 threads -> 4 waves
    const int lane = threadIdx.x & 63;
    const int wave = threadIdx.x >> 6;
    if (lane == 0) wsum[wave] = s;
    __syncthreads();
    if (threadIdx.x == 0) {
        float bs = wsum[0] + wsum[1] + wsum[2] + wsum[3];
        atomicAdd(accum, bs);
    }
}

__global__ void finalize_kernel(const float* __restrict__ accum,
                                float* __restrict__ out) {
    out[0] = accum[0] / (float)NTOT;
}

extern "C" void kernel_launch(void* const* d_in, const int* in_sizes, int n_in,
                              void* d_out, int out_size, void* d_ws, size_t ws_size,
                              hipStream_t stream) {
    const float* inp  = (const float*)d_in[0];  // input_data  (8,3,512,512)
    const float* tar  = (const float*)d_in[1];  // target_data (8,3,512,512)
    const float* ref  = (const float*)d_in[2];  // ref_data    (8,3,512,512)
    const float* msrc = (const float*)d_in[3];  // mask_src    (8,1,512,512)
    const float* mtar = (const float*)d_in[4];  // mask_tar    (8,1,512,512)

    char* ws = (char*)d_ws;
    int*   hs    = (int*)(ws + WS_HS_OFF);
    int*   hr    = (int*)(ws + WS_HR_OFF);
    float* lut   = (float*)(ws + WS_LUT_OFF);
    float* accum = (float*)(ws + WS_ACC_OFF);

    hipMemsetAsync(d_ws, 0, WS_BYTES, stream);

    hist_kernel<<<dim3(32, BC), 256, 0, stream>>>(ref, tar, msrc, mtar, hs, hr);
    lut_kernel<<<BC, 256, 0, stream>>>(hs, hr, lut);
    loss_kernel<<<2048, 256, 0, stream>>>(inp, ref, msrc, lut, accum);
    finalize_kernel<<<1, 1, 0, stream>>>(accum, (float*)d_out);
}